// Round 1
// baseline (172.374 us; speedup 1.0000x reference)
//
#include <hip/hip_runtime.h>
#include <math.h>

// ws layout:
//   [0..31]   header: double lik_sum; double rank_sum; unsigned long long pair_cnt;
//             float m_g; float n_events;
//   [32.. ]   float ex[N]  (exp(r_i - m_g))
struct WsHeader {
    double lik_sum;
    double rank_sum;
    unsigned long long pair_cnt;
    float m_g;
    float n_events;
};

__global__ __launch_bounds__(1024)
void prep_kernel(const float* __restrict__ r,
                 const int* __restrict__ e,
                 float* __restrict__ ws, int n) {
    __shared__ float smax[1024];
    __shared__ int   scnt[1024];
    int tid = threadIdx.x;
    float m = -INFINITY;
    int c = 0;
    for (int i = tid; i < n; i += 1024) {
        m = fmaxf(m, r[i]);
        c += (e[i] == 1);
    }
    smax[tid] = m;
    scnt[tid] = c;
    __syncthreads();
    for (int s = 512; s > 0; s >>= 1) {
        if (tid < s) {
            smax[tid] = fmaxf(smax[tid], smax[tid + s]);
            scnt[tid] += scnt[tid + s];
        }
        __syncthreads();
    }
    WsHeader* h = (WsHeader*)ws;
    if (tid == 0) {
        h->lik_sum  = 0.0;
        h->rank_sum = 0.0;
        h->pair_cnt = 0ull;
        h->m_g      = smax[0];
        h->n_events = (float)scnt[0];
    }
    float mg = smax[0];
    float* ex = ws + 8;  // 32-byte header
    for (int i = tid; i < n; i += 1024) {
        ex[i] = expf(r[i] - mg);
    }
}

// One wave (64 lanes) per 'a'. Each wave scans all b in float4 chunks.
__global__ __launch_bounds__(256)
void pair_kernel(const float* __restrict__ t,
                 const float* __restrict__ r,
                 const int* __restrict__ e,
                 float* __restrict__ ws, int n) {
    WsHeader* h = (WsHeader*)ws;
    const float* __restrict__ ex = ws + 8;

    const int lane = threadIdx.x & 63;
    const int a = blockIdx.x * 4 + (threadIdx.x >> 6);
    if (a >= n) return;

    const float t_a = t[a];
    const float r_a = r[a];
    const int   e_a = e[a];
    const float mg  = h->m_g;

    float sgt = 0.f;   // sum exp(r_b - mg) over t_b > t_a
    float ssuf = 0.f;  // sum exp(r_b - mg) over suffix set
    int   cnt  = 0;    // count t_b > t_a

    int k = 0;
    const int nvec = n & ~255;  // multiple of 256 handled vectorized
    for (; k < nvec; k += 256) {
        const int idx = k + lane * 4;
        const float4 t4 = *(const float4*)(t + idx);
        const float4 x4 = *(const float4*)(ex + idx);
        #pragma unroll
        for (int j = 0; j < 4; ++j) {
            const float tb = (j == 0) ? t4.x : (j == 1) ? t4.y : (j == 2) ? t4.z : t4.w;
            const float xb = (j == 0) ? x4.x : (j == 1) ? x4.y : (j == 2) ? x4.z : x4.w;
            const int b = idx + j;
            const bool gt  = (tb > t_a);
            const bool suf = (tb < t_a) || ((tb == t_a) && (b >= a));
            cnt  += gt ? 1 : 0;
            sgt  += gt ? xb : 0.f;
            ssuf += suf ? xb : 0.f;
        }
    }
    // scalar tail (n not multiple of 256)
    for (int b = k + lane; b < n; b += 64) {
        const float tb = t[b];
        const float xb = ex[b];
        const bool gt  = (tb > t_a);
        const bool suf = (tb < t_a) || ((tb == t_a) && (b >= a));
        cnt  += gt ? 1 : 0;
        sgt  += gt ? xb : 0.f;
        ssuf += suf ? xb : 0.f;
    }

    // wave reduction (64 lanes)
    #pragma unroll
    for (int off = 32; off > 0; off >>= 1) {
        sgt  += __shfl_xor(sgt,  off);
        ssuf += __shfl_xor(ssuf, off);
        cnt  += __shfl_xor(cnt,  off);
    }

    if (lane == 0 && e_a == 1) {
        atomicAdd(&h->lik_sum,  (double)(r_a - mg - logf(ssuf)));
        atomicAdd(&h->rank_sum, (double)(expf(mg - r_a) * sgt));
        atomicAdd(&h->pair_cnt, (unsigned long long)cnt);
    }
}

__global__ void finalize_kernel(const float* __restrict__ ws,
                                float* __restrict__ out) {
    const WsHeader* h = (const WsHeader*)ws;
    const float lik  = (float)h->lik_sum;
    const float rank = (float)h->rank_sum;
    const float pc   = (float)h->pair_cnt;
    const float likelihood_loss = -lik / (h->n_events + 1e-8f);
    const float ranking_loss = (pc > 0.f) ? (rank / fmaxf(pc, 1.f)) : rank;
    out[0] = likelihood_loss + 0.2f * ranking_loss;
}

extern "C" void kernel_launch(void* const* d_in, const int* in_sizes, int n_in,
                              void* d_out, int out_size, void* d_ws, size_t ws_size,
                              hipStream_t stream) {
    const float* risk   = (const float*)d_in[0];
    const float* times  = (const float*)d_in[1];
    const int*   events = (const int*)d_in[2];
    float* ws  = (float*)d_ws;
    float* out = (float*)d_out;
    const int n = in_sizes[0];

    prep_kernel<<<1, 1024, 0, stream>>>(risk, events, ws, n);
    const int blocks = (n + 3) / 4;  // one wave per 'a', 4 waves per block
    pair_kernel<<<blocks, 256, 0, stream>>>(times, risk, events, ws, n);
    finalize_kernel<<<1, 1, 0, stream>>>(ws, out);
}

// Round 2
// 36.560 us; speedup vs baseline: 4.7148x; 4.7148x over previous
//
#include <hip/hip_runtime.h>
#include <math.h>

#define MAX_N_LDS 8192

// ws layout:
//   [0..31]                header (WsHeader)
//   [32 .. 32+4n)          float ex[n]  (exp(r_i - m_g))
//   [align8 after ex ..)   double partials[3 * nblocks]  {lik, rank, cnt}
struct WsHeader {
    double lik_sum;            // used only by fallback path
    double rank_sum;
    unsigned long long pair_cnt;
    float m_g;
    float n_events;
};

__global__ __launch_bounds__(1024)
void prep_kernel(const float* __restrict__ r,
                 const int* __restrict__ e,
                 float* __restrict__ ws, int n) {
    __shared__ float smax[1024];
    __shared__ int   scnt[1024];
    int tid = threadIdx.x;
    float m = -INFINITY;
    int c = 0;
    for (int i = tid; i < n; i += 1024) {
        m = fmaxf(m, r[i]);
        c += (e[i] == 1);
    }
    smax[tid] = m;
    scnt[tid] = c;
    __syncthreads();
    for (int s = 512; s > 0; s >>= 1) {
        if (tid < s) {
            smax[tid] = fmaxf(smax[tid], smax[tid + s]);
            scnt[tid] += scnt[tid + s];
        }
        __syncthreads();
    }
    WsHeader* h = (WsHeader*)ws;
    if (tid == 0) {
        h->lik_sum  = 0.0;
        h->rank_sum = 0.0;
        h->pair_cnt = 0ull;
        h->m_g      = smax[0];
        h->n_events = (float)scnt[0];
    }
    float mg = smax[0];
    float* ex = ws + 8;
    for (int i = tid; i < n; i += 1024) {
        ex[i] = expf(r[i] - mg);
    }
}

// Main path (n <= MAX_N_LDS): stage (t, ex) interleaved in LDS; each wave
// handles 4 'a' values; per-block partial sums -> partials[].
__global__ __launch_bounds__(256)
void pair2_kernel(const float* __restrict__ t,
                  const float* __restrict__ r,
                  const int* __restrict__ e,
                  const float* __restrict__ ws,
                  double* __restrict__ partials, int n) {
    __shared__ float2 tx[MAX_N_LDS];   // 64 KB; reused as reduction scratch at the end
    const WsHeader* h = (const WsHeader*)ws;
    const float* __restrict__ ex = ws + 8;
    const int tid  = threadIdx.x;
    const int lane = tid & 63;
    const int wid  = tid >> 6;

    for (int i = tid; i < n; i += 256)
        tx[i] = make_float2(t[i], ex[i]);
    __syncthreads();

    const float mg = h->m_g;
    const int a0 = blockIdx.x * 16 + wid * 4;

    float ta[4], ra[4];
    int   ea[4];
    #pragma unroll
    for (int j = 0; j < 4; ++j) {
        int a = a0 + j;
        bool ok = a < n;
        int ai = ok ? a : 0;
        ta[j] = t[ai];
        ra[j] = r[ai];
        ea[j] = ok ? e[ai] : 0;
    }

    float sgt[4] = {0.f, 0.f, 0.f, 0.f};
    float ssf[4] = {0.f, 0.f, 0.f, 0.f};
    int   cnt[4] = {0, 0, 0, 0};

    int base = 0;
    for (; base + 128 <= n; base += 128) {
        const int b0 = base + lane;
        const int b1 = base + 64 + lane;
        const float2 p0 = tx[b0];
        const float2 p1 = tx[b1];
        #pragma unroll
        for (int j = 0; j < 4; ++j) {
            const int aj = a0 + j;
            {
                const bool gt = p0.x > ta[j];
                const bool sf = (p0.x < ta[j]) || ((p0.x == ta[j]) && (b0 >= aj));
                cnt[j] += gt ? 1 : 0;
                sgt[j] += gt ? p0.y : 0.f;
                ssf[j] += sf ? p0.y : 0.f;
            }
            {
                const bool gt = p1.x > ta[j];
                const bool sf = (p1.x < ta[j]) || ((p1.x == ta[j]) && (b1 >= aj));
                cnt[j] += gt ? 1 : 0;
                sgt[j] += gt ? p1.y : 0.f;
                ssf[j] += sf ? p1.y : 0.f;
            }
        }
    }
    for (int b = base + lane; b < n; b += 64) {
        const float2 p = tx[b];
        #pragma unroll
        for (int j = 0; j < 4; ++j) {
            const int aj = a0 + j;
            const bool gt = p.x > ta[j];
            const bool sf = (p.x < ta[j]) || ((p.x == ta[j]) && (b >= aj));
            cnt[j] += gt ? 1 : 0;
            sgt[j] += gt ? p.y : 0.f;
            ssf[j] += sf ? p.y : 0.f;
        }
    }

    // 64-lane butterfly reduction of the 12 accumulators
    #pragma unroll
    for (int off = 32; off > 0; off >>= 1) {
        #pragma unroll
        for (int j = 0; j < 4; ++j) {
            sgt[j] += __shfl_xor(sgt[j], off);
            ssf[j] += __shfl_xor(ssf[j], off);
            cnt[j] += __shfl_xor(cnt[j], off);
        }
    }

    __syncthreads();                    // all tx reads done; reuse LDS
    double* red = (double*)tx;          // red[wid*3 + {0,1,2}]
    if (lane == 0) {
        double lik = 0.0, rnk = 0.0, pc = 0.0;
        #pragma unroll
        for (int j = 0; j < 4; ++j) {
            if (ea[j] == 1) {
                lik += (double)(ra[j] - mg - logf(ssf[j]));
                rnk += (double)(expf(mg - ra[j]) * sgt[j]);
                pc  += (double)cnt[j];
            }
        }
        red[wid * 3 + 0] = lik;
        red[wid * 3 + 1] = rnk;
        red[wid * 3 + 2] = pc;
    }
    __syncthreads();
    if (tid == 0) {
        partials[blockIdx.x * 3 + 0] = red[0] + red[3] + red[6] + red[9];
        partials[blockIdx.x * 3 + 1] = red[1] + red[4] + red[7] + red[10];
        partials[blockIdx.x * 3 + 2] = red[2] + red[5] + red[8] + red[11];
    }
}

__global__ __launch_bounds__(256)
void finalize2_kernel(const float* __restrict__ ws,
                      const double* __restrict__ partials,
                      int nblocks, float* __restrict__ out) {
    __shared__ double sl[256], sr[256], sc[256];
    const WsHeader* h = (const WsHeader*)ws;
    const int tid = threadIdx.x;
    double lik = 0.0, rnk = 0.0, pc = 0.0;
    for (int i = tid; i < nblocks; i += 256) {
        lik += partials[i * 3 + 0];
        rnk += partials[i * 3 + 1];
        pc  += partials[i * 3 + 2];
    }
    sl[tid] = lik; sr[tid] = rnk; sc[tid] = pc;
    __syncthreads();
    for (int s = 128; s > 0; s >>= 1) {
        if (tid < s) { sl[tid] += sl[tid + s]; sr[tid] += sr[tid + s]; sc[tid] += sc[tid + s]; }
        __syncthreads();
    }
    if (tid == 0) {
        const float likf = (float)sl[0];
        const float rnkf = (float)sr[0];
        const float pcf  = (float)sc[0];
        const float likelihood_loss = -likf / (h->n_events + 1e-8f);
        const float ranking_loss = (pcf > 0.f) ? (rnkf / fmaxf(pcf, 1.f)) : rnkf;
        out[0] = likelihood_loss + 0.2f * ranking_loss;
    }
}

// ---------- fallback path for n > MAX_N_LDS (unchanged round-1 kernels) ----------
__global__ __launch_bounds__(256)
void pair_kernel(const float* __restrict__ t,
                 const float* __restrict__ r,
                 const int* __restrict__ e,
                 float* __restrict__ ws, int n) {
    WsHeader* h = (WsHeader*)ws;
    const float* __restrict__ ex = ws + 8;
    const int lane = threadIdx.x & 63;
    const int a = blockIdx.x * 4 + (threadIdx.x >> 6);
    if (a >= n) return;
    const float t_a = t[a];
    const float r_a = r[a];
    const int   e_a = e[a];
    const float mg  = h->m_g;
    float sgt = 0.f, ssuf = 0.f;
    int cnt = 0;
    for (int b = lane; b < n; b += 64) {
        const float tb = t[b];
        const float xb = ex[b];
        const bool gt  = (tb > t_a);
        const bool suf = (tb < t_a) || ((tb == t_a) && (b >= a));
        cnt  += gt ? 1 : 0;
        sgt  += gt ? xb : 0.f;
        ssuf += suf ? xb : 0.f;
    }
    #pragma unroll
    for (int off = 32; off > 0; off >>= 1) {
        sgt  += __shfl_xor(sgt,  off);
        ssuf += __shfl_xor(ssuf, off);
        cnt  += __shfl_xor(cnt,  off);
    }
    if (lane == 0 && e_a == 1) {
        atomicAdd(&h->lik_sum,  (double)(r_a - mg - logf(ssuf)));
        atomicAdd(&h->rank_sum, (double)(expf(mg - r_a) * sgt));
        atomicAdd(&h->pair_cnt, (unsigned long long)cnt);
    }
}

__global__ void finalize_kernel(const float* __restrict__ ws,
                                float* __restrict__ out) {
    const WsHeader* h = (const WsHeader*)ws;
    const float lik  = (float)h->lik_sum;
    const float rank = (float)h->rank_sum;
    const float pc   = (float)h->pair_cnt;
    const float likelihood_loss = -lik / (h->n_events + 1e-8f);
    const float ranking_loss = (pc > 0.f) ? (rank / fmaxf(pc, 1.f)) : rank;
    out[0] = likelihood_loss + 0.2f * ranking_loss;
}

extern "C" void kernel_launch(void* const* d_in, const int* in_sizes, int n_in,
                              void* d_out, int out_size, void* d_ws, size_t ws_size,
                              hipStream_t stream) {
    const float* risk   = (const float*)d_in[0];
    const float* times  = (const float*)d_in[1];
    const int*   events = (const int*)d_in[2];
    float* ws  = (float*)d_ws;
    float* out = (float*)d_out;
    const int n = in_sizes[0];

    prep_kernel<<<1, 1024, 0, stream>>>(risk, events, ws, n);

    if (n <= MAX_N_LDS) {
        const int nblocks = (n + 15) / 16;   // 16 'a' per block (4 waves x 4)
        double* partials = (double*)((char*)d_ws + 32 + (size_t)((n + 1) & ~1) * 4);
        pair2_kernel<<<nblocks, 256, 0, stream>>>(times, risk, events, ws, partials, n);
        finalize2_kernel<<<1, 256, 0, stream>>>(ws, partials, nblocks, out);
    } else {
        const int blocks = (n + 3) / 4;
        pair_kernel<<<blocks, 256, 0, stream>>>(times, risk, events, ws, n);
        finalize_kernel<<<1, 1, 0, stream>>>(ws, out);
    }
}

// Round 3
// 28.172 us; speedup vs baseline: 6.1187x; 1.2978x over previous
//
#include <hip/hip_runtime.h>
#include <math.h>

#define MAXN 8192

// Main path ws layout: double partials[4 * nblocks] at ws base:
//   [b*4+0]=lik, [b*4+1]=rank, [b*4+2]=pair_cnt, [b*4+3]=n_events (same in every block)
// Fallback path (n > MAXN) uses the round-1 layout (header at ws base).

// ---------------- main fused kernel ----------------
// One launch does everything except the final 256-block reduction:
// each block stages (t_bits, exp(r)) for ALL n into LDS (computing exp itself),
// counts n_events itself, then its 8 waves each scan all b for 4 'a' values.
__global__ __launch_bounds__(512)
void pair_fused(const float* __restrict__ t,
                const float* __restrict__ r,
                const int* __restrict__ e,
                double* __restrict__ partials, int n) {
    __shared__ uint2 sd[MAXN];          // 64 KB: (float_bits(t_i), bits(exp(r_i)))
    __shared__ double red[8][3];
    __shared__ int evred[8];

    const int tid  = threadIdx.x;
    const int lane = tid & 63;
    const int wid  = tid >> 6;          // 0..7

    // stage + per-block n_events (every block covers the full range)
    int evsum = 0;
    for (int i = tid; i < n; i += 512) {
        evsum += (e[i] == 1);
        sd[i] = make_uint2(__float_as_uint(t[i]), __float_as_uint(__expf(r[i])));
    }
    const int npad = (n + 127) & ~127;  // n <= MAXN so npad <= MAXN
    for (int i = n + tid; i < npad; i += 512)
        sd[i] = make_uint2(0u, 0u);     // t_bits=0 -> never 'gt'; ex=0 -> inert in sums
    __syncthreads();

    // this wave's 4 'a' values
    const int a0 = blockIdx.x * 32 + wid * 4;
    unsigned int ka_hi[4];
    unsigned long long ka[4];
    float ra[4];
    int   ea[4];
    #pragma unroll
    for (int j = 0; j < 4; ++j) {
        const int a = a0 + j;
        const bool ok = (a < n);
        const int ai = ok ? a : 0;
        ka_hi[j] = __float_as_uint(t[ai]);
        ka[j] = ((unsigned long long)ka_hi[j] << 32) | (unsigned long long)(0x7FFFFFFFu - (unsigned)ai);
        ra[j] = r[ai];
        ea[j] = ok ? e[ai] : 0;
    }

    float sgt[4] = {0.f, 0.f, 0.f, 0.f};
    float ssf[4] = {0.f, 0.f, 0.f, 0.f};
    int   cnt[4] = {0, 0, 0, 0};        // wave-uniform via ballot

    // suffix predicate == one u64 compare on key (t_bits << 32) | (0x7FFFFFFF - b)
    unsigned int lo0 = 0x7FFFFFFFu - (unsigned)lane;
    unsigned int lo1 = 0x7FFFFFFFu - 64u - (unsigned)lane;
    for (int base = 0; base < npad; base += 128) {
        const uint2 p0 = sd[base + lane];
        const uint2 p1 = sd[base + 64 + lane];
        const float x0 = __uint_as_float(p0.y);
        const float x1 = __uint_as_float(p1.y);
        const unsigned long long k0 = ((unsigned long long)p0.x << 32) | (unsigned long long)lo0;
        const unsigned long long k1 = ((unsigned long long)p1.x << 32) | (unsigned long long)lo1;
        #pragma unroll
        for (int j = 0; j < 4; ++j) {
            const bool gt0 = p0.x > ka_hi[j];
            const bool gt1 = p1.x > ka_hi[j];
            sgt[j] += gt0 ? x0 : 0.f;
            sgt[j] += gt1 ? x1 : 0.f;
            ssf[j] += (k0 <= ka[j]) ? x0 : 0.f;
            ssf[j] += (k1 <= ka[j]) ? x1 : 0.f;
            cnt[j] += __popcll(__ballot(gt0)) + __popcll(__ballot(gt1));
        }
        lo0 -= 128u;
        lo1 -= 128u;
    }

    // butterfly reduce the float accumulators (cnt already wave-uniform)
    #pragma unroll
    for (int off = 32; off > 0; off >>= 1) {
        #pragma unroll
        for (int j = 0; j < 4; ++j) {
            sgt[j] += __shfl_xor(sgt[j], off);
            ssf[j] += __shfl_xor(ssf[j], off);
        }
    }
    evsum += __shfl_xor(evsum, 32); evsum += __shfl_xor(evsum, 16);
    evsum += __shfl_xor(evsum, 8);  evsum += __shfl_xor(evsum, 4);
    evsum += __shfl_xor(evsum, 2);  evsum += __shfl_xor(evsum, 1);

    if (lane == 0) {
        double lik = 0.0, rnk = 0.0, pc = 0.0;
        #pragma unroll
        for (int j = 0; j < 4; ++j) {
            if (ea[j] == 1) {
                lik += (double)(ra[j] - __logf(ssf[j]));
                rnk += (double)(__expf(-ra[j]) * sgt[j]);
                pc  += (double)cnt[j];
            }
        }
        red[wid][0] = lik; red[wid][1] = rnk; red[wid][2] = pc;
        evred[wid] = evsum;
    }
    __syncthreads();
    if (tid == 0) {
        double lik = 0.0, rnk = 0.0, pc = 0.0;
        int ev = 0;
        #pragma unroll
        for (int w = 0; w < 8; ++w) {
            lik += red[w][0]; rnk += red[w][1]; pc += red[w][2]; ev += evred[w];
        }
        partials[blockIdx.x * 4 + 0] = lik;
        partials[blockIdx.x * 4 + 1] = rnk;
        partials[blockIdx.x * 4 + 2] = pc;
        partials[blockIdx.x * 4 + 3] = (double)ev;
    }
}

__global__ __launch_bounds__(256)
void finalize3_kernel(const double* __restrict__ partials,
                      int nblocks, float* __restrict__ out) {
    __shared__ double sl[256], sr[256], sc[256];
    const int tid = threadIdx.x;
    double lik = 0.0, rnk = 0.0, pc = 0.0;
    for (int i = tid; i < nblocks; i += 256) {
        lik += partials[i * 4 + 0];
        rnk += partials[i * 4 + 1];
        pc  += partials[i * 4 + 2];
    }
    sl[tid] = lik; sr[tid] = rnk; sc[tid] = pc;
    __syncthreads();
    for (int s = 128; s > 0; s >>= 1) {
        if (tid < s) { sl[tid] += sl[tid + s]; sr[tid] += sr[tid + s]; sc[tid] += sc[tid + s]; }
        __syncthreads();
    }
    if (tid == 0) {
        const float nev  = (float)partials[3];
        const float likf = (float)sl[0];
        const float rnkf = (float)sr[0];
        const float pcf  = (float)sc[0];
        const float likelihood_loss = -likf / (nev + 1e-8f);
        const float ranking_loss = (pcf > 0.f) ? (rnkf / fmaxf(pcf, 1.f)) : rnkf;
        out[0] = likelihood_loss + 0.2f * ranking_loss;
    }
}

// ---------------- fallback path (n > MAXN), unchanged from round 1 ----------------
struct WsHeader {
    double lik_sum;
    double rank_sum;
    unsigned long long pair_cnt;
    float m_g;
    float n_events;
};

__global__ __launch_bounds__(1024)
void prep_kernel(const float* __restrict__ r,
                 const int* __restrict__ e,
                 float* __restrict__ ws, int n) {
    __shared__ float smax[1024];
    __shared__ int   scnt[1024];
    int tid = threadIdx.x;
    float m = -INFINITY;
    int c = 0;
    for (int i = tid; i < n; i += 1024) {
        m = fmaxf(m, r[i]);
        c += (e[i] == 1);
    }
    smax[tid] = m;
    scnt[tid] = c;
    __syncthreads();
    for (int s = 512; s > 0; s >>= 1) {
        if (tid < s) {
            smax[tid] = fmaxf(smax[tid], smax[tid + s]);
            scnt[tid] += scnt[tid + s];
        }
        __syncthreads();
    }
    WsHeader* h = (WsHeader*)ws;
    if (tid == 0) {
        h->lik_sum  = 0.0;
        h->rank_sum = 0.0;
        h->pair_cnt = 0ull;
        h->m_g      = smax[0];
        h->n_events = (float)scnt[0];
    }
    float mg = smax[0];
    float* ex = ws + 8;
    for (int i = tid; i < n; i += 1024) {
        ex[i] = expf(r[i] - mg);
    }
}

__global__ __launch_bounds__(256)
void pair_kernel(const float* __restrict__ t,
                 const float* __restrict__ r,
                 const int* __restrict__ e,
                 float* __restrict__ ws, int n) {
    WsHeader* h = (WsHeader*)ws;
    const float* __restrict__ ex = ws + 8;
    const int lane = threadIdx.x & 63;
    const int a = blockIdx.x * 4 + (threadIdx.x >> 6);
    if (a >= n) return;
    const float t_a = t[a];
    const float r_a = r[a];
    const int   e_a = e[a];
    const float mg  = h->m_g;
    float sgt = 0.f, ssuf = 0.f;
    int cnt = 0;
    for (int b = lane; b < n; b += 64) {
        const float tb = t[b];
        const float xb = ex[b];
        const bool gt  = (tb > t_a);
        const bool suf = (tb < t_a) || ((tb == t_a) && (b >= a));
        cnt  += gt ? 1 : 0;
        sgt  += gt ? xb : 0.f;
        ssuf += suf ? xb : 0.f;
    }
    #pragma unroll
    for (int off = 32; off > 0; off >>= 1) {
        sgt  += __shfl_xor(sgt,  off);
        ssuf += __shfl_xor(ssuf, off);
        cnt  += __shfl_xor(cnt,  off);
    }
    if (lane == 0 && e_a == 1) {
        atomicAdd(&h->lik_sum,  (double)(r_a - mg - logf(ssuf)));
        atomicAdd(&h->rank_sum, (double)(expf(mg - r_a) * sgt));
        atomicAdd(&h->pair_cnt, (unsigned long long)cnt);
    }
}

__global__ void finalize_kernel(const float* __restrict__ ws,
                                float* __restrict__ out) {
    const WsHeader* h = (const WsHeader*)ws;
    const float lik  = (float)h->lik_sum;
    const float rank = (float)h->rank_sum;
    const float pc   = (float)h->pair_cnt;
    const float likelihood_loss = -lik / (h->n_events + 1e-8f);
    const float ranking_loss = (pc > 0.f) ? (rank / fmaxf(pc, 1.f)) : rank;
    out[0] = likelihood_loss + 0.2f * ranking_loss;
}

extern "C" void kernel_launch(void* const* d_in, const int* in_sizes, int n_in,
                              void* d_out, int out_size, void* d_ws, size_t ws_size,
                              hipStream_t stream) {
    const float* risk   = (const float*)d_in[0];
    const float* times  = (const float*)d_in[1];
    const int*   events = (const int*)d_in[2];
    float* out = (float*)d_out;
    const int n = in_sizes[0];

    if (n <= MAXN) {
        double* partials = (double*)d_ws;
        const int nblocks = (n + 31) / 32;   // 32 'a' per block (8 waves x 4)
        pair_fused<<<nblocks, 512, 0, stream>>>(times, risk, events, partials, n);
        finalize3_kernel<<<1, 256, 0, stream>>>(partials, nblocks, out);
    } else {
        float* ws = (float*)d_ws;
        prep_kernel<<<1, 1024, 0, stream>>>(risk, events, ws, n);
        const int blocks = (n + 3) / 4;
        pair_kernel<<<blocks, 256, 0, stream>>>(times, risk, events, ws, n);
        finalize_kernel<<<1, 1, 0, stream>>>(ws, out);
    }
}

// Round 4
// 26.668 us; speedup vs baseline: 6.4637x; 1.0564x over previous
//
#include <hip/hip_runtime.h>
#include <math.h>

#define CH 2048   // b-chunk staged in LDS: 2048 x uint2 = 16 KB

// partials[blk*4 + {0,1,2,3}] = {lik, rank, pair_cnt, n_events}
// Every block computes full-range n_events redundantly (identical values).
__global__ __launch_bounds__(256)
void pair_scan(const float* __restrict__ t,
               const float* __restrict__ r,
               const int* __restrict__ e,
               double* __restrict__ partials, int n) {
    __shared__ uint2  sd[CH];
    __shared__ double red[4][3];
    __shared__ int    evred[4];

    const int tid  = threadIdx.x;
    const int lane = tid & 63;
    const int wid  = tid >> 6;          // 0..3

    // this wave's 2 'a' values
    const int a0 = blockIdx.x * 8 + wid * 2;
    unsigned int ka_hi[2];
    unsigned long long ka[2];
    float ra[2];
    int   ea[2];
#pragma unroll
    for (int j = 0; j < 2; ++j) {
        const int a   = a0 + j;
        const bool ok = (a < n);
        const int ai  = ok ? a : 0;
        ka_hi[j] = __float_as_uint(t[ai]);
        // suffix predicate (t_b < t_a) || (t_b == t_a && b >= a)  <=>  k_b <= k_a
        // with k = (t_bits << 32) | (0x7FFFFFFF - index)
        ka[j] = ((unsigned long long)ka_hi[j] << 32) |
                (unsigned long long)(0x7FFFFFFFu - (unsigned)ai);
        ra[j] = r[ai];
        ea[j] = ok ? e[ai] : 0;
    }

    float sgt[2] = {0.f, 0.f};          // sum exp(r_b) over t_b > t_a
    float ssf[2] = {0.f, 0.f};          // sum exp(r_b) over suffix set
    int   cnt[2] = {0, 0};              // wave-uniform via ballot
    int   evsum  = 0;

    const int nch = (n + CH - 1) / CH;
    for (int c = 0; c < nch; ++c) {
        const int base = c * CH;
        // stage chunk (pad with t_bits=0, ex=0 -> inert for every predicate/sum)
#pragma unroll
        for (int k = 0; k < CH / 256; ++k) {
            const int li = tid + k * 256;
            const int gi = base + li;
            uint2 v = make_uint2(0u, 0u);
            if (gi < n) {
                v.x = __float_as_uint(t[gi]);
                v.y = __float_as_uint(__expf(r[gi]));
                evsum += (e[gi] == 1);
            }
            sd[li] = v;
        }
        __syncthreads();

        unsigned int lo0 = 0x7FFFFFFFu - (unsigned)(base + lane);
        unsigned int lo1 = lo0 - 64u;
        for (int off = 0; off < CH; off += 128) {
            const uint2 p0 = sd[off + lane];
            const uint2 p1 = sd[off + 64 + lane];
            const float x0 = __uint_as_float(p0.y);
            const float x1 = __uint_as_float(p1.y);
            const unsigned long long k0 =
                ((unsigned long long)p0.x << 32) | (unsigned long long)lo0;
            const unsigned long long k1 =
                ((unsigned long long)p1.x << 32) | (unsigned long long)lo1;
#pragma unroll
            for (int j = 0; j < 2; ++j) {
                const bool gt0 = p0.x > ka_hi[j];
                const bool gt1 = p1.x > ka_hi[j];
                sgt[j] += gt0 ? x0 : 0.f;
                sgt[j] += gt1 ? x1 : 0.f;
                ssf[j] += (k0 <= ka[j]) ? x0 : 0.f;
                ssf[j] += (k1 <= ka[j]) ? x1 : 0.f;
                cnt[j] += __popcll(__ballot(gt0)) + __popcll(__ballot(gt1));
            }
            lo0 -= 128u;
            lo1 -= 128u;
        }
        __syncthreads();
    }

    // 64-lane butterfly reduction (cnt already wave-uniform)
#pragma unroll
    for (int off = 32; off > 0; off >>= 1) {
#pragma unroll
        for (int j = 0; j < 2; ++j) {
            sgt[j] += __shfl_xor(sgt[j], off);
            ssf[j] += __shfl_xor(ssf[j], off);
        }
        evsum += __shfl_xor(evsum, off);
    }

    if (lane == 0) {
        double lik = 0.0, rnk = 0.0, pc = 0.0;
#pragma unroll
        for (int j = 0; j < 2; ++j) {
            if (ea[j] == 1) {
                lik += (double)(ra[j] - __logf(ssf[j]));
                rnk += (double)(__expf(-ra[j]) * sgt[j]);
                pc  += (double)cnt[j];
            }
        }
        red[wid][0] = lik; red[wid][1] = rnk; red[wid][2] = pc;
        evred[wid] = evsum;
    }
    __syncthreads();
    if (tid == 0) {
        const double lik = red[0][0] + red[1][0] + red[2][0] + red[3][0];
        const double rnk = red[0][1] + red[1][1] + red[2][1] + red[3][1];
        const double pc  = red[0][2] + red[1][2] + red[2][2] + red[3][2];
        const int    ev  = evred[0] + evred[1] + evred[2] + evred[3];
        partials[blockIdx.x * 4 + 0] = lik;
        partials[blockIdx.x * 4 + 1] = rnk;
        partials[blockIdx.x * 4 + 2] = pc;
        partials[blockIdx.x * 4 + 3] = (double)ev;
    }
}

__global__ __launch_bounds__(256)
void finalize3_kernel(const double* __restrict__ partials,
                      int nblocks, float* __restrict__ out) {
    __shared__ double sl[256], sr[256], sc[256];
    const int tid = threadIdx.x;
    double lik = 0.0, rnk = 0.0, pc = 0.0;
    for (int i = tid; i < nblocks; i += 256) {
        lik += partials[i * 4 + 0];
        rnk += partials[i * 4 + 1];
        pc  += partials[i * 4 + 2];
    }
    sl[tid] = lik; sr[tid] = rnk; sc[tid] = pc;
    __syncthreads();
    for (int s = 128; s > 0; s >>= 1) {
        if (tid < s) { sl[tid] += sl[tid + s]; sr[tid] += sr[tid + s]; sc[tid] += sc[tid + s]; }
        __syncthreads();
    }
    if (tid == 0) {
        const float nev  = (float)partials[3];   // identical in every block
        const float likf = (float)sl[0];
        const float rnkf = (float)sr[0];
        const float pcf  = (float)sc[0];
        const float likelihood_loss = -likf / (nev + 1e-8f);
        const float ranking_loss = (pcf > 0.f) ? (rnkf / fmaxf(pcf, 1.f)) : rnkf;
        out[0] = likelihood_loss + 0.2f * ranking_loss;
    }
}

extern "C" void kernel_launch(void* const* d_in, const int* in_sizes, int n_in,
                              void* d_out, int out_size, void* d_ws, size_t ws_size,
                              hipStream_t stream) {
    const float* risk   = (const float*)d_in[0];
    const float* times  = (const float*)d_in[1];
    const int*   events = (const int*)d_in[2];
    float* out = (float*)d_out;
    const int n = in_sizes[0];

    double* partials = (double*)d_ws;
    const int nblocks = (n + 7) / 8;    // 8 'a' per block (4 waves x 2)
    pair_scan<<<nblocks, 256, 0, stream>>>(times, risk, events, partials, n);
    finalize3_kernel<<<1, 256, 0, stream>>>(partials, nblocks, out);
}

// Round 5
// 19.310 us; speedup vs baseline: 8.9269x; 1.3811x over previous
//
#include <hip/hip_runtime.h>
#include <math.h>

#define CH 8192           // b-table staged per chunk (SoA: 32KB t_bits + 32KB ex)
#define TPB 512           // 8 waves per block
#define A_PER_WAVE 2
#define A_PER_BLOCK 16    // 8 waves * 2

// partials[blk*4 + {0,1,2,3}] = {lik, rank, pair_cnt, n_events}
__global__ __launch_bounds__(TPB)
void pair_scan(const float* __restrict__ t,
               const float* __restrict__ r,
               const int*   __restrict__ e,
               double* __restrict__ partials, int n) {
    __shared__ __align__(16) unsigned int st[CH];   // t bits
    __shared__ __align__(16) float        sx[CH];   // exp(r)
    __shared__ double red[8][3];
    __shared__ float  swsum[8];
    __shared__ int    swev[8];

    const int tid  = threadIdx.x;
    const int lane = tid & 63;
    const int wid  = tid >> 6;

    // this wave's a-values
    const int a0 = blockIdx.x * A_PER_BLOCK + wid * A_PER_WAVE;
    unsigned int ta[A_PER_WAVE];
    float ra[A_PER_WAVE];
    int   ea[A_PER_WAVE];
#pragma unroll
    for (int j = 0; j < A_PER_WAVE; ++j) {
        const int a = a0 + j;
        const bool ok = (a < n);
        const int ai = ok ? a : 0;
        ta[j] = __float_as_uint(t[ai]);   // t >= 0 -> u32 order == float order
        ra[j] = r[ai];
        ea[j] = ok ? e[ai] : 0;
    }

    float sgt[A_PER_WAVE] = {0.f, 0.f};   // sum exp(r_b) over strictly t_b > t_a
    int   cnt[A_PER_WAVE] = {0, 0};       // count    over strictly t_b > t_a (wave-uniform)
    float xsum  = 0.f;                    // this thread's staged-ex partial (-> S_total)
    int   evsum = 0;

    const int nch = (n + CH - 1) / CH;
    for (int c = 0; c < nch; ++c) {
        const int base = c * CH;
        // ---- stage chunk as SoA, vectorized float4/int4; pad inert (t=0, ex=0) ----
#pragma unroll
        for (int k = 0; k < CH / (TPB * 4); ++k) {
            const int li = tid * 4 + k * TPB * 4;
            const int gi = base + li;
            uint4  tb;
            float4 xb;
            if (gi + 3 < n) {
                const float4 tv = *(const float4*)(t + gi);
                const float4 rv = *(const float4*)(r + gi);
                const int4   ev = *(const int4*)(e + gi);
                tb = make_uint4(__float_as_uint(tv.x), __float_as_uint(tv.y),
                                __float_as_uint(tv.z), __float_as_uint(tv.w));
                xb = make_float4(__expf(rv.x), __expf(rv.y), __expf(rv.z), __expf(rv.w));
                evsum += (ev.x == 1) + (ev.y == 1) + (ev.z == 1) + (ev.w == 1);
                xsum  += xb.x + xb.y + xb.z + xb.w;
            } else {
                float tvv[4], xvv[4];
#pragma unroll
                for (int m = 0; m < 4; ++m) {
                    const int g = gi + m;
                    if (g < n) {
                        tvv[m] = t[g];
                        xvv[m] = __expf(r[g]);
                        evsum += (e[g] == 1);
                        xsum  += xvv[m];
                    } else { tvv[m] = 0.f; xvv[m] = 0.f; }
                }
                tb = make_uint4(__float_as_uint(tvv[0]), __float_as_uint(tvv[1]),
                                __float_as_uint(tvv[2]), __float_as_uint(tvv[3]));
                xb = make_float4(xvv[0], xvv[1], xvv[2], xvv[3]);
            }
            *(uint4*)(st + li)  = tb;
            *(float4*)(sx + li) = xb;
        }
        __syncthreads();

        // ---- scan: 512 b per wave-iter via 4x ds_read_b128, one predicate per pair ----
        for (int it = 0; it < CH / 512; ++it) {
            const int o = it * 512 + lane * 4;
            const uint4  t4a = *(const uint4*)(st + o);
            const uint4  t4b = *(const uint4*)(st + o + 256);
            const float4 x4a = *(const float4*)(sx + o);
            const float4 x4b = *(const float4*)(sx + o + 256);
#pragma unroll
            for (int j = 0; j < A_PER_WAVE; ++j) {
                const unsigned int tj = ta[j];
                bool g;
                g = (t4a.x > tj); sgt[j] += g ? x4a.x : 0.f; cnt[j] += __popcll(__ballot(g));
                g = (t4a.y > tj); sgt[j] += g ? x4a.y : 0.f; cnt[j] += __popcll(__ballot(g));
                g = (t4a.z > tj); sgt[j] += g ? x4a.z : 0.f; cnt[j] += __popcll(__ballot(g));
                g = (t4a.w > tj); sgt[j] += g ? x4a.w : 0.f; cnt[j] += __popcll(__ballot(g));
                g = (t4b.x > tj); sgt[j] += g ? x4b.x : 0.f; cnt[j] += __popcll(__ballot(g));
                g = (t4b.y > tj); sgt[j] += g ? x4b.y : 0.f; cnt[j] += __popcll(__ballot(g));
                g = (t4b.z > tj); sgt[j] += g ? x4b.z : 0.f; cnt[j] += __popcll(__ballot(g));
                g = (t4b.w > tj); sgt[j] += g ? x4b.w : 0.f; cnt[j] += __popcll(__ballot(g));
            }
        }
        __syncthreads();   // safe to restage next chunk
    }

    // ---- wave butterflies (cnt already wave-uniform via ballot) ----
#pragma unroll
    for (int off = 32; off > 0; off >>= 1) {
#pragma unroll
        for (int j = 0; j < A_PER_WAVE; ++j)
            sgt[j] += __shfl_xor(sgt[j], off);
        xsum  += __shfl_xor(xsum, off);
        evsum += __shfl_xor(evsum, off);
    }
    if (lane == 0) { swsum[wid] = xsum; swev[wid] = evsum; }
    __syncthreads();

    if (lane == 0) {
        float S = 0.f;
        int   EV = 0;
#pragma unroll
        for (int w = 0; w < 8; ++w) { S += swsum[w]; EV += swev[w]; }
        double lik = 0.0, rnk = 0.0, pc = 0.0;
#pragma unroll
        for (int j = 0; j < A_PER_WAVE; ++j) {
            if (ea[j] == 1) {
                // ssf = sum over {t_b <= t_a} = S_total - sgt; exact lower bound: own term
                float ssf = S - sgt[j];
                ssf = fmaxf(ssf, __expf(ra[j]));
                lik += (double)(ra[j] - __logf(ssf));
                rnk += (double)(__expf(-ra[j]) * sgt[j]);
                pc  += (double)cnt[j];
            }
        }
        red[wid][0] = lik; red[wid][1] = rnk; red[wid][2] = pc;
        if (wid == 0) {
            // stash EV for tid==0 epilogue via swev[0] (block total)
            swev[0] = EV;
        }
    }
    __syncthreads();
    if (tid == 0) {
        double lik = 0.0, rnk = 0.0, pc = 0.0;
#pragma unroll
        for (int w = 0; w < 8; ++w) { lik += red[w][0]; rnk += red[w][1]; pc += red[w][2]; }
        partials[blockIdx.x * 4 + 0] = lik;
        partials[blockIdx.x * 4 + 1] = rnk;
        partials[blockIdx.x * 4 + 2] = pc;
        partials[blockIdx.x * 4 + 3] = (double)swev[0];
    }
}

// single-wave finalize: 512 blocks * 4 doubles = 16 KB
__global__ __launch_bounds__(64)
void finalize4_kernel(const double* __restrict__ partials,
                      int nblocks, float* __restrict__ out) {
    const int lane = threadIdx.x;
    double lik = 0.0, rnk = 0.0, pc = 0.0;
    for (int i = lane; i < nblocks; i += 64) {
        lik += partials[i * 4 + 0];
        rnk += partials[i * 4 + 1];
        pc  += partials[i * 4 + 2];
    }
#pragma unroll
    for (int off = 32; off > 0; off >>= 1) {
        lik += __shfl_xor(lik, off);
        rnk += __shfl_xor(rnk, off);
        pc  += __shfl_xor(pc,  off);
    }
    if (lane == 0) {
        const float nev  = (float)partials[3];   // block 0's full-range n_events
        const float likf = (float)lik;
        const float rnkf = (float)rnk;
        const float pcf  = (float)pc;
        const float likelihood_loss = -likf / (nev + 1e-8f);
        const float ranking_loss = (pcf > 0.f) ? (rnkf / fmaxf(pcf, 1.f)) : rnkf;
        out[0] = likelihood_loss + 0.2f * ranking_loss;
    }
}

extern "C" void kernel_launch(void* const* d_in, const int* in_sizes, int n_in,
                              void* d_out, int out_size, void* d_ws, size_t ws_size,
                              hipStream_t stream) {
    const float* risk   = (const float*)d_in[0];
    const float* times  = (const float*)d_in[1];
    const int*   events = (const int*)d_in[2];
    float* out = (float*)d_out;
    const int n = in_sizes[0];

    double* partials = (double*)d_ws;
    const int nblocks = (n + A_PER_BLOCK - 1) / A_PER_BLOCK;
    pair_scan<<<nblocks, TPB, 0, stream>>>(times, risk, events, partials, n);
    finalize4_kernel<<<1, 64, 0, stream>>>(partials, nblocks, out);
}